// Round 1
// baseline (291.019 us; speedup 1.0000x reference)
//
#include <hip/hip_runtime.h>
#include <hip/hip_cooperative_groups.h>

namespace cg = cooperative_groups;

// Problem constants (from setup_inputs)
#define V_    50000
#define D_    128
#define HOPS_ 3
#define B_    16
#define LC_   256
#define MC_   8
#define LK_   512
#define MK_   8

typedef __bf16  bf16x8  __attribute__((ext_vector_type(8)));
typedef unsigned short ushort8 __attribute__((ext_vector_type(8)));
typedef unsigned short ushort4v __attribute__((ext_vector_type(4)));
typedef float   floatx4 __attribute__((ext_vector_type(4)));

__device__ inline unsigned short f2bf(float f) {
    union { float f; unsigned u; } x; x.f = f;
    unsigned r = x.u + 0x7FFFu + ((x.u >> 16) & 1u);   // RNE
    return (unsigned short)(r >> 16);
}

__device__ inline floatx4 mfma_bf16(ushort8 a, ushort8 b, floatx4 c) {
    return __builtin_amdgcn_mfma_f32_16x16x32_bf16(
        __builtin_bit_cast(bf16x8, a), __builtin_bit_cast(bf16x8, b), c, 0, 0, 0);
}

// ---------------------------------------------------------------------------
// Fused cooperative kernel: 768 blocks x 512 threads, exactly 3 blocks/CU
// (LDS 49.7 KB -> 149 KB/CU; __launch_bounds__(512,6) caps VGPRs for 24
// waves/CU so cooperative co-residency holds).
//
// Phase 1 (per block, before grid.sync):
//   1a: zero its slice of d_out (first 256 blocks, one float4 each thread)
//   1b: gather 32 kf rows [lt*32, lt*32+32) of its OWN group g -> kf global
//       + stage bf16 rows in LDS scratch (overlaid on phase-1-dead p_s)
//   1c: gather its own cf tile (16 bags) -> LDS (overlaid on att_s; handed
//       across the sync so attn needs no global cf round-trip)
//   1d: transpose LDS scratch -> kfT global
//   cf's 50 MB of random reads now overlap kf's 100 MB instead of being
//   serialized behind a kernel boundary; the boundary drain itself is gone.
//
// Phase 2 (after grid.sync): identical attention as before.
//   kf writes/reads stay in the same bx&7 class -> same-XCD L2 locality;
//   correctness does NOT depend on the XCD mapping (grid.sync orders
//   device-wide).
// ---------------------------------------------------------------------------
__global__ __launch_bounds__(512, 6) void fused_kernel(
    const int* __restrict__ conv_seqs, const int* __restrict__ kb_arr,
    const float* __restrict__ Ct, const float* __restrict__ Kt,
    unsigned short* __restrict__ kf, unsigned short* __restrict__ kfT,
    float* __restrict__ out)
{
    constexpr int AS = 516;                  // fp32 score stride
    constexpr int PS = 520;                  // bf16 p stride
    __shared__ float att_s[16][AS];          // 33.0 KB
    __shared__ unsigned short p_s[16][PS];   // 16.6 KB
    __shared__ float rowinv_s[16];

    // Overlays (all temporally disjoint, sequenced by barriers):
    //   cf_s   : 4224 B at att_s base; written phase 1c, read (afrag) at
    //            phase-2 start, dead before Phase A overwrites att_s.
    //   tile2  : 8704 B transpose scratch on p_s; phase 1 only (softmax
    //            writes p_s much later).
    unsigned short* cf_s = (unsigned short*)&att_s[0][0];
    unsigned short (*tile2)[136] = (unsigned short (*)[136])&p_s[0][0];

    const int tid  = threadIdx.x;
    const int wave = tid >> 6;               // 0..7
    const int lane = tid & 63;
    const int quad = lane >> 4;              // 0..3
    const int l16  = lane & 15;

    // XCD-swizzle decode: all 16 l-tiles of a (hop,b) share bx%8
    const int gl  = blockIdx.x & 7;
    const int s_  = blockIdx.x >> 3;         // 0..95
    const int lt  = s_ / 6;                  // 0..15
    const int gh  = s_ % 6;                  // 0..5
    const int g   = gh * 8 + gl;             // 0..47 = hop*16+b
    const int hop = g >> 4;
    const int b   = g & 15;
    const int l0  = lt * 16;
    const int row0 = lt * 32;                // kf rows this block produces

    // -------- phase 1a: zero d_out (fire-and-forget) --------
    {
        const int zi = blockIdx.x * 512 + tid;
        if (zi < LC_ * B_ * D_ / 4)
            reinterpret_cast<float4*>(out)[zi] = make_float4(0.f, 0.f, 0.f, 0.f);
    }

    // -------- phase 1b: kf gather, 32 rows, 16-lane clusters --------
    {
        const int r = tid >> 4;              // 0..31
        const int s = tid & 15;
        const int* idxp = kb_arr + (size_t)(b * LK_ + row0 + r) * MK_;
        const float* table = Kt + (size_t)hop * V_ * D_;
        unsigned short* dst = kf + ((size_t)g * LK_ + row0 + r) * D_;

        const int myidx = idxp[s & 7];       // 8 idx per row, loaded twice
        int idxs[8];
        #pragma unroll
        for (int m = 0; m < 8; ++m)
            idxs[m] = __shfl(myidx, (lane & 48) + m);  // 16-lane cluster base

        float4 a0 = make_float4(0.f, 0.f, 0.f, 0.f);
        float4 a1 = make_float4(0.f, 0.f, 0.f, 0.f);
        #pragma unroll
        for (int m = 0; m < 8; ++m) {
            const float4* rowp = (const float4*)(table + (size_t)idxs[m] * D_);
            float4 v0 = rowp[s * 2];
            float4 v1 = rowp[s * 2 + 1];
            a0.x += v0.x; a0.y += v0.y; a0.z += v0.z; a0.w += v0.w;
            a1.x += v1.x; a1.y += v1.y; a1.z += v1.z; a1.w += v1.w;
        }

        ushort8 o;
        o[0] = f2bf(a0.x); o[1] = f2bf(a0.y); o[2] = f2bf(a0.z); o[3] = f2bf(a0.w);
        o[4] = f2bf(a1.x); o[5] = f2bf(a1.y); o[6] = f2bf(a1.z); o[7] = f2bf(a1.w);
        *(ushort8*)(dst + s * 8) = o;        // cluster writes 256B contiguous
        *(ushort8*)&tile2[r][s * 8] = o;     // stage for transpose
    }

    // -------- phase 1c: cf gather -> cf_s (overlaps 1b's loads via ILP) ----
    {
        const int bag = tid >> 5;            // 16 bags
        const int sl  = tid & 31;
        const int d0  = sl * 4;
        const int* idxp = conv_seqs + (size_t)(b * LC_ + l0 + bag) * MC_;
        const float* table = Ct + (size_t)hop * V_ * D_;
        float4 acc = make_float4(0.f, 0.f, 0.f, 0.f);
        #pragma unroll
        for (int m = 0; m < 8; ++m) {
            const float4 v = *(const float4*)(table + (size_t)idxp[m] * D_ + d0);
            acc.x += v.x; acc.y += v.y; acc.z += v.z; acc.w += v.w;
        }
        ushort4v oc;
        oc[0] = f2bf(acc.x); oc[1] = f2bf(acc.y);
        oc[2] = f2bf(acc.z); oc[3] = f2bf(acc.w);
        *(ushort4v*)&cf_s[bag * 132 + d0] = oc;
    }

    __syncthreads();                         // tile2 + cf_s complete

    // -------- phase 1d: transpose tile2 -> kfT --------
    {
        const int d   = tid >> 2;            // 0..127
        const int sub = tid & 3;             // 8-row subtile
        ushort8 t8;
        #pragma unroll
        for (int i = 0; i < 8; ++i) t8[i] = tile2[sub * 8 + i][d];
        // thread-quads write 64B contiguous per d-row
        *(ushort8*)(kfT + ((size_t)g * D_ + d) * LK_ + row0 + sub * 8) = t8;
    }

    cg::this_grid().sync();                  // all kf/kfT/out-zero visible

    // ======== phase 2: attention (unchanged structure) ========
    const unsigned short* kf_h  = kf  + (size_t)g * LK_ * D_;
    const unsigned short* kfT_h = kfT + (size_t)g * D_ * LK_;

    // A-fragments (cf rows) from LDS handoff, reused across all 32 n-tiles
    ushort8 afrag[4];
    #pragma unroll
    for (int ks = 0; ks < 4; ++ks)
        afrag[ks] = *(const ushort8*)&cf_s[l16 * 132 + ks * 32 + quad * 8];
    __syncthreads();                         // cf_s dead before att_s writes

    // -------- Phase A: att = cf @ kf^T --------
    #pragma unroll
    for (int t = 0; t < 4; ++t) {
        const int nt = wave * 4 + t;         // 8 waves x 4 = 32 n-tiles
        floatx4 acc = {0.f, 0.f, 0.f, 0.f};
        #pragma unroll
        for (int ks = 0; ks < 4; ++ks) {
            ushort8 bfrag = *(const ushort8*)(kf_h + (nt * 16 + l16) * 128 + ks * 32 + quad * 8);
            acc = mfma_bf16(afrag[ks], bfrag, acc);
        }
        #pragma unroll
        for (int rr = 0; rr < 4; ++rr)
            att_s[quad * 4 + rr][nt * 16 + l16] = acc[rr];
    }
    __syncthreads();

    // -------- softmax: wave handles rows 2*wave, 2*wave+1; emit bf16 p_s ----
    #pragma unroll
    for (int rr = 0; rr < 2; ++rr) {
        const int row = wave * 2 + rr;
        float v[8];
        float mx = -1e30f;
        #pragma unroll
        for (int j = 0; j < 8; ++j) {
            v[j] = att_s[row][lane + j * 64];
            mx = fmaxf(mx, v[j]);
        }
        #pragma unroll
        for (int off = 32; off; off >>= 1) mx = fmaxf(mx, __shfl_xor(mx, off));
        float sum = 0.f;
        #pragma unroll
        for (int j = 0; j < 8; ++j) {
            float e = __expf(v[j] - mx);
            p_s[row][lane + j * 64] = f2bf(e);
            sum += e;
        }
        #pragma unroll
        for (int off = 32; off; off >>= 1) sum += __shfl_xor(sum, off);
        if (lane == 0) rowinv_s[row] = 1.0f / sum;
    }
    __syncthreads();

    // -------- Phase B: out_tile = p @ kf  (wave owns d-tile = wave) --------
    floatx4 pacc = {0.f, 0.f, 0.f, 0.f};
    #pragma unroll
    for (int ks = 0; ks < 16; ++ks) {
        ushort8 pa    = *(const ushort8*)&p_s[l16][ks * 32 + quad * 8];
        ushort8 bfrag = *(const ushort8*)(kfT_h + (size_t)(wave * 16 + l16) * 512 + ks * 32 + quad * 8);
        pacc = mfma_bf16(pa, bfrag, pacc);
    }

    // out layout: [Lc, B, D]; hop-sum via atomics (measured free in R4;
    // all 3 hops of a b share bx&7 -> same-XCD L2 for the atomic lines)
    const int d = wave * 16 + l16;
    #pragma unroll
    for (int rr = 0; rr < 4; ++rr)
        atomicAdd(&out[(((size_t)(l0 + quad * 4 + rr)) * 16 + b) * 128 + d],
                  pacc[rr] * rowinv_s[quad * 4 + rr]);
}

// ---------------------------------------------------------------------------
// Fallback path (verbatim previous two-kernel version) — used only if the
// cooperative launch fails synchronously.
// ---------------------------------------------------------------------------
__global__ __launch_bounds__(256, 6) void gather_kernel(
    const int* __restrict__ kb_arr, const float* __restrict__ Kt,
    unsigned short* __restrict__ kf, unsigned short* __restrict__ kfT,
    float4* __restrict__ out4)
{
    __shared__ unsigned short tile[16][136];

    const int tid  = threadIdx.x;
    const int bx   = blockIdx.x;

    constexpr int KBLK = HOPS_ * B_ * (LK_ / 16);   // 1536

    if (bx >= KBLK) {
        out4[(size_t)(bx - KBLK) * 256 + tid] = make_float4(0.f, 0.f, 0.f, 0.f);
        return;
    }

    const int r    = tid >> 4;
    const int s    = tid & 15;
    const int lane = tid & 63;

    const int hop  = bx / (B_ * 32);
    const int rem  = bx % (B_ * 32);
    const int b    = rem >> 5;
    const int row0 = (rem & 31) * 16;
    const int g    = hop * B_ + b;

    const int* idxp = kb_arr + (size_t)(b * LK_ + row0 + r) * MK_;
    const float* table = Kt + (size_t)hop * V_ * D_;
    unsigned short* dst = kf + ((size_t)g * LK_ + row0 + r) * D_;

    const int myidx = idxp[s & 7];
    int idxs[8];
    #pragma unroll
    for (int m = 0; m < 8; ++m)
        idxs[m] = __shfl(myidx, (lane & 48) + m);

    float4 a0 = make_float4(0.f, 0.f, 0.f, 0.f);
    float4 a1 = make_float4(0.f, 0.f, 0.f, 0.f);

    #pragma unroll
    for (int m = 0; m < 8; ++m) {
        const float4* rowp = (const float4*)(table + (size_t)idxs[m] * D_);
        float4 v0 = rowp[s * 2];
        float4 v1 = rowp[s * 2 + 1];
        a0.x += v0.x; a0.y += v0.y; a0.z += v0.z; a0.w += v0.w;
        a1.x += v1.x; a1.y += v1.y; a1.z += v1.z; a1.w += v1.w;
    }

    ushort8 o;
    o[0] = f2bf(a0.x); o[1] = f2bf(a0.y); o[2] = f2bf(a0.z); o[3] = f2bf(a0.w);
    o[4] = f2bf(a1.x); o[5] = f2bf(a1.y); o[6] = f2bf(a1.z); o[7] = f2bf(a1.w);
    *(ushort8*)(dst + s * 8) = o;

    *(ushort8*)&tile[r][s * 8] = o;
    __syncthreads();
    const int d    = tid >> 1;
    const int half = tid & 1;
    unsigned short* tdst = kfT + ((size_t)g * D_ + d) * LK_ + row0 + half * 8;
    ushort8 t8;
    #pragma unroll
    for (int i = 0; i < 8; ++i) t8[i] = tile[half * 8 + i][d];
    *(ushort8*)(tdst) = t8;
}

__global__ __launch_bounds__(512) void attn_kernel(
    const int* __restrict__ conv_seqs, const float* __restrict__ Ct,
    const unsigned short* __restrict__ kf, const unsigned short* __restrict__ kfT,
    float* __restrict__ out)
{
    constexpr int AS = 516;
    constexpr int PS = 520;
    __shared__ float att_s[16][AS];
    __shared__ unsigned short p_s[16][PS];
    __shared__ float rowinv_s[16];

    unsigned short* cf_s = &p_s[0][0];

    const int tid  = threadIdx.x;
    const int wave = tid >> 6;
    const int lane = tid & 63;
    const int quad = lane >> 4;
    const int l16  = lane & 15;

    const int gl  = blockIdx.x & 7;
    const int s_  = blockIdx.x >> 3;
    const int lt  = s_ / 6;
    const int gh  = s_ % 6;
    const int g   = gh * 8 + gl;
    const int hop = g >> 4;
    const int b   = g & 15;
    const int l0  = lt * 16;

    const unsigned short* kf_h  = kf  + ((size_t)g) * 512 * 128;
    const unsigned short* kfT_h = kfT + ((size_t)g) * 128 * 512;

    {
        const int bag = tid >> 5;
        const int sl  = tid & 31;
        const int d0  = sl * 4;
        const int* idxp = conv_seqs + (size_t)(b * LC_ + l0 + bag) * MC_;
        const float* table = Ct + (size_t)hop * V_ * D_;
        float4 acc = make_float4(0.f, 0.f, 0.f, 0.f);
        #pragma unroll
        for (int m = 0; m < 8; ++m) {
            const float4 v = *(const float4*)(table + (size_t)idxp[m] * D_ + d0);
            acc.x += v.x; acc.y += v.y; acc.z += v.z; acc.w += v.w;
        }
        ushort4v oc;
        oc[0] = f2bf(acc.x); oc[1] = f2bf(acc.y);
        oc[2] = f2bf(acc.z); oc[3] = f2bf(acc.w);
        *(ushort4v*)&cf_s[bag * 132 + d0] = oc;
    }
    __syncthreads();

    ushort8 afrag[4];
    #pragma unroll
    for (int ks = 0; ks < 4; ++ks)
        afrag[ks] = *(const ushort8*)&cf_s[l16 * 132 + ks * 32 + quad * 8];

    #pragma unroll
    for (int t = 0; t < 4; ++t) {
        const int nt = wave * 4 + t;
        floatx4 acc = {0.f, 0.f, 0.f, 0.f};
        #pragma unroll
        for (int ks = 0; ks < 4; ++ks) {
            ushort8 bfrag = *(const ushort8*)(kf_h + (nt * 16 + l16) * 128 + ks * 32 + quad * 8);
            acc = mfma_bf16(afrag[ks], bfrag, acc);
        }
        #pragma unroll
        for (int rr = 0; rr < 4; ++rr)
            att_s[quad * 4 + rr][nt * 16 + l16] = acc[rr];
    }
    __syncthreads();

    #pragma unroll
    for (int rr = 0; rr < 2; ++rr) {
        const int row = wave * 2 + rr;
        float v[8];
        float mx = -1e30f;
        #pragma unroll
        for (int j = 0; j < 8; ++j) {
            v[j] = att_s[row][lane + j * 64];
            mx = fmaxf(mx, v[j]);
        }
        #pragma unroll
        for (int off = 32; off; off >>= 1) mx = fmaxf(mx, __shfl_xor(mx, off));
        float sum = 0.f;
        #pragma unroll
        for (int j = 0; j < 8; ++j) {
            float e = __expf(v[j] - mx);
            p_s[row][lane + j * 64] = f2bf(e);
            sum += e;
        }
        #pragma unroll
        for (int off = 32; off; off >>= 1) sum += __shfl_xor(sum, off);
        if (lane == 0) rowinv_s[row] = 1.0f / sum;
    }
    __syncthreads();

    floatx4 pacc = {0.f, 0.f, 0.f, 0.f};
    #pragma unroll
    for (int ks = 0; ks < 16; ++ks) {
        ushort8 pa    = *(const ushort8*)&p_s[l16][ks * 32 + quad * 8];
        ushort8 bfrag = *(const ushort8*)(kfT_h + (size_t)(wave * 16 + l16) * 512 + ks * 32 + quad * 8);
        pacc = mfma_bf16(pa, bfrag, pacc);
    }

    const int d = wave * 16 + l16;
    #pragma unroll
    for (int rr = 0; rr < 4; ++rr)
        atomicAdd(&out[(((size_t)(l0 + quad * 4 + rr)) * 16 + b) * 128 + d],
                  pacc[rr] * rowinv_s[quad * 4 + rr]);
}

extern "C" void kernel_launch(void* const* d_in, const int* in_sizes, int n_in,
                              void* d_out, int out_size, void* d_ws, size_t ws_size,
                              hipStream_t stream) {
    (void)in_sizes; (void)n_in; (void)out_size; (void)ws_size;
    const int*   conv_seqs = (const int*)d_in[0];
    const int*   kb_arr    = (const int*)d_in[1];
    const float* C         = (const float*)d_in[2];
    const float* K         = (const float*)d_in[3];

    // ws layout (bf16): kf [3][16][512][128], kfT [3][16][128][512]
    unsigned short* kf  = (unsigned short*)d_ws;
    unsigned short* kfT = kf + (size_t)HOPS_ * B_ * LK_ * D_;
    float* out = (float*)d_out;

    void* args[7];
    args[0] = (void*)&conv_seqs;
    args[1] = (void*)&kb_arr;
    args[2] = (void*)&C;
    args[3] = (void*)&K;
    args[4] = (void*)&kf;
    args[5] = (void*)&kfT;
    args[6] = (void*)&out;

    hipError_t e = hipLaunchCooperativeKernel(
        reinterpret_cast<const void*>(&fused_kernel),
        dim3(768), dim3(512), args, 0, stream);

    if (e != hipSuccess) {
        // Fallback: previous verified two-kernel path
        hipLaunchKernelGGL(gather_kernel, dim3(2048), dim3(256), 0, stream,
                           kb_arr, K, kf, kfT, (float4*)out);
        hipLaunchKernelGGL(attn_kernel, dim3(768), dim3(512), 0, stream,
                           conv_seqs, C, kf, kfT, out);
    }
}

// Round 2
// 189.486 us; speedup vs baseline: 1.5358x; 1.5358x over previous
//
#include <hip/hip_runtime.h>

// Problem constants (from setup_inputs)
#define V_    50000
#define D_    128
#define HOPS_ 3
#define B_    16
#define LC_   256
#define MC_   8
#define LK_   512
#define MK_   8

typedef __bf16  bf16x8  __attribute__((ext_vector_type(8)));
typedef unsigned short ushort8 __attribute__((ext_vector_type(8)));
typedef unsigned short ushort4v __attribute__((ext_vector_type(4)));
typedef float   floatx4 __attribute__((ext_vector_type(4)));

__device__ inline unsigned short f2bf(float f) {
    union { float f; unsigned u; } x; x.f = f;
    unsigned r = x.u + 0x7FFFu + ((x.u >> 16) & 1u);   // RNE
    return (unsigned short)(r >> 16);
}

__device__ inline floatx4 mfma_bf16(ushort8 a, ushort8 b, floatx4 c) {
    return __builtin_amdgcn_mfma_f32_16x16x32_bf16(
        __builtin_bit_cast(bf16x8, a), __builtin_bit_cast(bf16x8, b), c, 0, 0, 0);
}

// ---------------------------------------------------------------------------
// Kernel 1: K-table embedding-bag gather + in-block kfT transpose + d_out
// zeroing.  REVISED from the 189.6us baseline for load ILP:
//   - 32-lane clusters cover one 512B table row (one float4/lane/token, so
//     all 8 token loads = 32 data VGPRs, fully in flight before accumulate).
//   - __launch_bounds__(512,4) -> VGPR cap 64 (the old (256,6) capped at 40,
//     which serialized loads -- proven by the fused-kernel experiment where
//     the same cap produced 678 GB/s latency-bound behavior).
//   - 64-VGPR kernels still get 8 waves/SIMD (occupancy halves above 64).
//   blocks [0,1536):     kf tiles (hop,b,ktile of 16 rows) + kfT transpose
//   blocks [1536,1792):  zero d_out (256 blocks x 512 thr x float4)
// ---------------------------------------------------------------------------
__global__ __launch_bounds__(512, 4) void gather_kernel(
    const int* __restrict__ kb_arr, const float* __restrict__ Kt,
    unsigned short* __restrict__ kf, unsigned short* __restrict__ kfT,
    float4* __restrict__ out4)
{
    __shared__ unsigned short tile[16][136];     // 4.35 KB, pad for transpose

    const int tid  = threadIdx.x;
    const int bx   = blockIdx.x;

    constexpr int KBLK = HOPS_ * B_ * (LK_ / 16);   // 1536

    if (bx >= KBLK) {                        // zero-out blocks
        out4[(size_t)(bx - KBLK) * 512 + tid] = make_float4(0.f, 0.f, 0.f, 0.f);
        return;
    }

    const int r    = tid >> 5;               // row in tile (0..15)
    const int s    = tid & 31;               // position in 32-lane cluster
    const int lane = tid & 63;

    const int hop  = bx / (B_ * 32);
    const int rem  = bx % (B_ * 32);
    const int b    = rem >> 5;
    const int row0 = (rem & 31) * 16;
    const int g    = hop * B_ + b;

    const int* idxp = kb_arr + (size_t)(b * LK_ + row0 + r) * MK_;
    const float* table = Kt + (size_t)hop * V_ * D_;
    unsigned short* dst = kf + ((size_t)g * LK_ + row0 + r) * D_;

    const int myidx = idxp[s & 7];           // 8 idx per row (loaded 4x)
    int idxs[8];
    #pragma unroll
    for (int m = 0; m < 8; ++m)
        idxs[m] = __shfl(myidx, (lane & 32) + m);    // 32-lane cluster base

    // issue ALL 8 row loads before accumulating (32 data VGPRs in flight)
    float4 v[8];
    #pragma unroll
    for (int m = 0; m < 8; ++m)
        v[m] = ((const float4*)(table + (size_t)idxs[m] * D_))[s];

    float4 a = make_float4(0.f, 0.f, 0.f, 0.f);
    #pragma unroll
    for (int m = 0; m < 8; ++m) {
        a.x += v[m].x; a.y += v[m].y; a.z += v[m].z; a.w += v[m].w;
    }

    ushort4v o;
    o[0] = f2bf(a.x); o[1] = f2bf(a.y); o[2] = f2bf(a.z); o[3] = f2bf(a.w);
    *(ushort4v*)(dst + s * 4) = o;           // cluster writes 256B contiguous

    // transpose through LDS -> kfT
    *(ushort4v*)&tile[r][s * 4] = o;
    __syncthreads();
    const int d   = tid >> 2;                // 0..127
    const int sub = tid & 3;                 // 4-row subtile of 16
    unsigned short* tdst = kfT + ((size_t)g * D_ + d) * LK_ + row0 + sub * 4;
    ushort4v t4;
    #pragma unroll
    for (int i = 0; i < 4; ++i) t4[i] = tile[sub * 4 + i][d];
    *(ushort4v*)(tdst) = t4;                 // thread-quads: 32B contiguous
}

// ---------------------------------------------------------------------------
// Kernel 2: attention, hop-parallel, XCD-swizzled, with in-kernel cf gather.
// (verbatim from the 189.6us verified baseline)
// One block per (hop, b, 16-query tile): 768 blocks x 512 thr (3 blocks/CU).
//   cf gather: 16 bags x 8 tokens of C-rows summed by 32 thr/bag -> bf16 LDS
//              (overlaid on p_s: cf dead before softmax writes p_s)
//   Phase A: att[16][512] = cf_tile @ kf^T  (fp32 scores -> att_s)
//   softmax: per-wave shuffle butterfly, 2 rows/wave; emits bf16 p_s
//   Phase B: p_s @ kfT fragments; 1/sum folded; hop-sum via atomicAdd.
// LDS 49.7 KB -> 3 blocks/CU.
// ---------------------------------------------------------------------------
__global__ __launch_bounds__(512) void attn_kernel(
    const int* __restrict__ conv_seqs, const float* __restrict__ Ct,
    const unsigned short* __restrict__ kf, const unsigned short* __restrict__ kfT,
    float* __restrict__ out)
{
    constexpr int AS = 516;                  // fp32 score stride
    constexpr int PS = 520;                  // bf16 p stride
    __shared__ float att_s[16][AS];          // 33.0 KB
    __shared__ unsigned short p_s[16][PS];   // 16.6 KB (also hosts cf tile)
    __shared__ float rowinv_s[16];

    // cf tile overlay on p_s: element (bag,d) at p_s flat [bag*132 + d]
    unsigned short* cf_s = &p_s[0][0];

    const int tid  = threadIdx.x;
    const int wave = tid >> 6;               // 0..7
    const int lane = tid & 63;
    const int quad = lane >> 4;              // 0..3
    const int l16  = lane & 15;

    // XCD-swizzle decode: all 16 l-tiles of a (hop,b) share bx%8
    const int gl  = blockIdx.x & 7;
    const int s_  = blockIdx.x >> 3;         // 0..95
    const int lt  = s_ / 6;                  // 0..15
    const int gh  = s_ % 6;                  // 0..5
    const int g   = gh * 8 + gl;             // 0..47 = hop*16+b
    const int hop = g >> 4;
    const int b   = g & 15;
    const int l0  = lt * 16;

    const unsigned short* kf_h  = kf  + ((size_t)g) * 512 * 128;
    const unsigned short* kfT_h = kfT + ((size_t)g) * 128 * 512;

    // -------- cf gather: bag = tid>>5 (16 bags), 32 thr/bag, 4 d-elems -----
    {
        const int bag = tid >> 5;
        const int sl  = tid & 31;
        const int d0  = sl * 4;
        const int* idxp = conv_seqs + (size_t)(b * LC_ + l0 + bag) * MC_;
        const float* table = Ct + (size_t)hop * V_ * D_;
        float4 acc = make_float4(0.f, 0.f, 0.f, 0.f);
        #pragma unroll
        for (int m = 0; m < 8; ++m) {
            const float4 v = *(const float4*)(table + (size_t)idxp[m] * D_ + d0);
            acc.x += v.x; acc.y += v.y; acc.z += v.z; acc.w += v.w;
        }
        ushort4v oc;
        oc[0] = f2bf(acc.x); oc[1] = f2bf(acc.y);
        oc[2] = f2bf(acc.z); oc[3] = f2bf(acc.w);
        *(ushort4v*)&cf_s[bag * 132 + d0] = oc;
    }
    __syncthreads();

    // A-fragments (cf rows), reused across all 32 n-tiles
    ushort8 afrag[4];
    #pragma unroll
    for (int ks = 0; ks < 4; ++ks)
        afrag[ks] = *(const ushort8*)&cf_s[l16 * 132 + ks * 32 + quad * 8];

    // -------- Phase A: att = cf @ kf^T --------
    #pragma unroll
    for (int t = 0; t < 4; ++t) {
        const int nt = wave * 4 + t;         // 8 waves x 4 = 32 n-tiles (512 k)
        floatx4 acc = {0.f, 0.f, 0.f, 0.f};
        #pragma unroll
        for (int ks = 0; ks < 4; ++ks) {
            ushort8 bfrag = *(const ushort8*)(kf_h + (nt * 16 + l16) * 128 + ks * 32 + quad * 8);
            acc = mfma_bf16(afrag[ks], bfrag, acc);
        }
        #pragma unroll
        for (int rr = 0; rr < 4; ++rr)
            att_s[quad * 4 + rr][nt * 16 + l16] = acc[rr];
    }
    __syncthreads();                         // also fences afrag reads of cf_s

    // -------- softmax: wave handles rows 2*wave, 2*wave+1; emit bf16 p_s ----
    #pragma unroll
    for (int rr = 0; rr < 2; ++rr) {
        const int row = wave * 2 + rr;
        float v[8];
        float mx = -1e30f;
        #pragma unroll
        for (int j = 0; j < 8; ++j) {
            v[j] = att_s[row][lane + j * 64];
            mx = fmaxf(mx, v[j]);
        }
        #pragma unroll
        for (int off = 32; off; off >>= 1) mx = fmaxf(mx, __shfl_xor(mx, off));
        float sum = 0.f;
        #pragma unroll
        for (int j = 0; j < 8; ++j) {
            float e = __expf(v[j] - mx);
            p_s[row][lane + j * 64] = f2bf(e);
            sum += e;
        }
        #pragma unroll
        for (int off = 32; off; off >>= 1) sum += __shfl_xor(sum, off);
        if (lane == 0) rowinv_s[row] = 1.0f / sum;
    }
    __syncthreads();

    // -------- Phase B: out_tile = p @ kf  (wave owns d-tile = wave) --------
    floatx4 pacc = {0.f, 0.f, 0.f, 0.f};
    #pragma unroll
    for (int ks = 0; ks < 16; ++ks) {
        ushort8 pa    = *(const ushort8*)&p_s[l16][ks * 32 + quad * 8];
        ushort8 bfrag = *(const ushort8*)(kfT_h + (size_t)(wave * 16 + l16) * 512 + ks * 32 + quad * 8);
        pacc = mfma_bf16(pa, bfrag, pacc);
    }

    // out layout: [Lc, B, D]; hop-sum via atomics (measured free in R4)
    const int d = wave * 16 + l16;
    #pragma unroll
    for (int rr = 0; rr < 4; ++rr)
        atomicAdd(&out[(((size_t)(l0 + quad * 4 + rr)) * 16 + b) * 128 + d],
                  pacc[rr] * rowinv_s[quad * 4 + rr]);
}

extern "C" void kernel_launch(void* const* d_in, const int* in_sizes, int n_in,
                              void* d_out, int out_size, void* d_ws, size_t ws_size,
                              hipStream_t stream) {
    (void)in_sizes; (void)n_in; (void)out_size; (void)ws_size;
    const int*   conv_seqs = (const int*)d_in[0];
    const int*   kb_arr    = (const int*)d_in[1];
    const float* C         = (const float*)d_in[2];
    const float* K         = (const float*)d_in[3];

    // ws layout (bf16): kf [3][16][512][128], kfT [3][16][128][512]
    unsigned short* kf  = (unsigned short*)d_ws;
    unsigned short* kfT = kf + (size_t)HOPS_ * B_ * LK_ * D_;
    float* out = (float*)d_out;

    // 1536 kf blocks + 256 zero-out blocks (512 threads each)
    hipLaunchKernelGGL(gather_kernel, dim3(1792), dim3(512), 0, stream,
                       kb_arr, K, kf, kfT, (float4*)out);
    hipLaunchKernelGGL(attn_kernel, dim3(768), dim3(512), 0, stream,
                       conv_seqs, C, kf, kfT, out);
}

// Round 3
// 188.131 us; speedup vs baseline: 1.5469x; 1.0072x over previous
//
#include <hip/hip_runtime.h>

// Problem constants (from setup_inputs)
#define V_    50000
#define D_    128
#define HOPS_ 3
#define B_    16
#define LC_   256
#define MC_   8
#define LK_   512
#define MK_   8

typedef __bf16  bf16x8  __attribute__((ext_vector_type(8)));
typedef unsigned short ushort8 __attribute__((ext_vector_type(8)));
typedef unsigned short ushort4v __attribute__((ext_vector_type(4)));
typedef float   floatx4 __attribute__((ext_vector_type(4)));

__device__ inline unsigned short f2bf(float f) {
    union { float f; unsigned u; } x; x.f = f;
    unsigned r = x.u + 0x7FFFu + ((x.u >> 16) & 1u);   // RNE
    return (unsigned short)(r >> 16);
}

__device__ inline floatx4 mfma_bf16(ushort8 a, ushort8 b, floatx4 c) {
    return __builtin_amdgcn_mfma_f32_16x16x32_bf16(
        __builtin_bit_cast(bf16x8, a), __builtin_bit_cast(bf16x8, b), c, 0, 0, 0);
}

// ---------------------------------------------------------------------------
// Kernel 1: ALL random-gather work in one dispatch (K-table + C-table reads
// overlap -> higher achieved HBM BW) + kfT transpose + d_out zeroing.
//   blocks [0,1536):        kf tiles (hop,b,ktile of 16 rows) + kfT transpose
//   blocks [1536,2304):     cf tiles (g,lt): 16 bags x 128d bf16 -> cf ws
//   blocks [2304,2560):     zero d_out (256 blocks x 512 thr x float4)
// Rationale (R1/R2 post-mortems): attn previously spent its head on 50 MB of
// random C-table reads serialized behind a kernel boundary; here they ride
// alongside the K-gather's 100 MB in a latency-bound dispatch. VGPR cap 64
// via __launch_bounds__(512,4) -- the (.,6)=40-VGPR cap proved fatal in R1.
// ---------------------------------------------------------------------------
__global__ __launch_bounds__(512, 4) void gather_kernel(
    const int* __restrict__ kb_arr, const int* __restrict__ conv_seqs,
    const float* __restrict__ Kt, const float* __restrict__ Ct,
    unsigned short* __restrict__ kf, unsigned short* __restrict__ kfT,
    unsigned short* __restrict__ cf, float4* __restrict__ out4)
{
    __shared__ unsigned short tile[16][136];     // 4.35 KB, pad for transpose

    const int tid  = threadIdx.x;
    const int bx   = blockIdx.x;

    constexpr int KBLK  = HOPS_ * B_ * (LK_ / 16);   // 1536
    constexpr int CFBLK = HOPS_ * B_ * (LC_ / 16);   // 768

    if (bx >= KBLK + CFBLK) {                // ---- zero-out blocks ----
        out4[(size_t)(bx - KBLK - CFBLK) * 512 + tid] =
            make_float4(0.f, 0.f, 0.f, 0.f);
        return;
    }

    if (bx >= KBLK) {                        // ---- cf gather blocks ----
        const int i   = bx - KBLK;           // 0..767 = g*16 + lt
        const int g   = i >> 4;
        const int lt  = i & 15;
        const int hop = g >> 4;
        const int b   = g & 15;
        const int bag = tid >> 5;            // 16 bags, 32 thr/bag
        const int d0  = (tid & 31) * 4;
        const int* idxp = conv_seqs + (size_t)(b * LC_ + lt * 16 + bag) * MC_;
        const float* table = Ct + (size_t)hop * V_ * D_;

        // issue all 8 token loads before accumulating (load ILP)
        float4 v[8];
        #pragma unroll
        for (int m = 0; m < 8; ++m)
            v[m] = *(const float4*)(table + (size_t)idxp[m] * D_ + d0);
        float4 acc = make_float4(0.f, 0.f, 0.f, 0.f);
        #pragma unroll
        for (int m = 0; m < 8; ++m) {
            acc.x += v[m].x; acc.y += v[m].y; acc.z += v[m].z; acc.w += v[m].w;
        }
        ushort4v oc;
        oc[0] = f2bf(acc.x); oc[1] = f2bf(acc.y);
        oc[2] = f2bf(acc.z); oc[3] = f2bf(acc.w);
        // cf ws layout: [i = g*16+lt][bag][d] bf16 -> 4 KB contiguous per tile
        *(ushort4v*)&cf[((size_t)i * 16 + bag) * 128 + d0] = oc;
        return;
    }

    // ---- kf gather blocks (verbatim from R2: 32-lane clusters, load ILP) ----
    const int r    = tid >> 5;               // row in tile (0..15)
    const int s    = tid & 31;               // position in 32-lane cluster
    const int lane = tid & 63;

    const int hop  = bx / (B_ * 32);
    const int rem  = bx % (B_ * 32);
    const int b    = rem >> 5;
    const int row0 = (rem & 31) * 16;
    const int g    = hop * B_ + b;

    const int* idxp = kb_arr + (size_t)(b * LK_ + row0 + r) * MK_;
    const float* table = Kt + (size_t)hop * V_ * D_;
    unsigned short* dst = kf + ((size_t)g * LK_ + row0 + r) * D_;

    const int myidx = idxp[s & 7];           // 8 idx per row (loaded 4x)
    int idxs[8];
    #pragma unroll
    for (int m = 0; m < 8; ++m)
        idxs[m] = __shfl(myidx, (lane & 32) + m);    // 32-lane cluster base

    float4 v[8];
    #pragma unroll
    for (int m = 0; m < 8; ++m)
        v[m] = ((const float4*)(table + (size_t)idxs[m] * D_))[s];

    float4 a = make_float4(0.f, 0.f, 0.f, 0.f);
    #pragma unroll
    for (int m = 0; m < 8; ++m) {
        a.x += v[m].x; a.y += v[m].y; a.z += v[m].z; a.w += v[m].w;
    }

    ushort4v o;
    o[0] = f2bf(a.x); o[1] = f2bf(a.y); o[2] = f2bf(a.z); o[3] = f2bf(a.w);
    *(ushort4v*)(dst + s * 4) = o;           // cluster writes 256B contiguous

    // transpose through LDS -> kfT
    *(ushort4v*)&tile[r][s * 4] = o;
    __syncthreads();
    const int d   = tid >> 2;                // 0..127
    const int sub = tid & 3;                 // 4-row subtile of 16
    unsigned short* tdst = kfT + ((size_t)g * D_ + d) * LK_ + row0 + sub * 4;
    ushort4v t4;
    #pragma unroll
    for (int i = 0; i < 4; ++i) t4[i] = tile[sub * 4 + i][d];
    *(ushort4v*)(tdst) = t4;                 // thread-quads: 32B contiguous
}

// ---------------------------------------------------------------------------
// Kernel 2: attention, hop-parallel, XCD-swizzled.  cf gather REMOVED from
// the head (now a coalesced 4 KB LDS fill from ws) -- the kernel is now pure
// L2-bound MFMA + softmax with no random-latency phase.
// One block per (hop, b, 16-query tile): 768 blocks x 512 thr (3 blocks/CU).
//   Phase A: att[16][512] = cf_tile @ kf^T  (fp32 scores -> att_s)
//   softmax: per-wave shuffle butterfly, 2 rows/wave; emits bf16 p_s
//   Phase B: p_s @ kfT fragments; 1/sum folded; hop-sum via atomicAdd.
// LDS 49.7 KB -> 3 blocks/CU.
// ---------------------------------------------------------------------------
__global__ __launch_bounds__(512) void attn_kernel(
    const unsigned short* __restrict__ cf,
    const unsigned short* __restrict__ kf, const unsigned short* __restrict__ kfT,
    float* __restrict__ out)
{
    constexpr int AS = 516;                  // fp32 score stride
    constexpr int PS = 520;                  // bf16 p stride
    __shared__ float att_s[16][AS];          // 33.0 KB
    __shared__ unsigned short p_s[16][PS];   // 16.6 KB (also hosts cf tile)
    __shared__ float rowinv_s[16];

    // cf tile overlay on p_s: element (bag,d) at p_s flat [bag*132 + d]
    unsigned short* cf_s = &p_s[0][0];

    const int tid  = threadIdx.x;
    const int wave = tid >> 6;               // 0..7
    const int lane = tid & 63;
    const int quad = lane >> 4;              // 0..3
    const int l16  = lane & 15;

    // XCD-swizzle decode: all 16 l-tiles of a (hop,b) share bx%8
    const int gl  = blockIdx.x & 7;
    const int s_  = blockIdx.x >> 3;         // 0..95
    const int lt  = s_ / 6;                  // 0..15
    const int gh  = s_ % 6;                  // 0..5
    const int g   = gh * 8 + gl;             // 0..47 = hop*16+b
    const int b   = g & 15;
    const int l0  = lt * 16;

    const unsigned short* kf_h  = kf  + ((size_t)g) * 512 * 128;
    const unsigned short* kfT_h = kfT + ((size_t)g) * 128 * 512;

    // -------- cf load: 4 KB coalesced from ws -> padded LDS layout --------
    {
        const int bag = tid >> 5;
        const int off = (tid & 31) * 4;
        const ushort4v vc = *(const ushort4v*)
            (cf + ((size_t)(g * 16 + lt) * 16 + bag) * 128 + off);
        *(ushort4v*)&cf_s[bag * 132 + off] = vc;
    }
    __syncthreads();

    // A-fragments (cf rows), reused across all 32 n-tiles
    ushort8 afrag[4];
    #pragma unroll
    for (int ks = 0; ks < 4; ++ks)
        afrag[ks] = *(const ushort8*)&cf_s[l16 * 132 + ks * 32 + quad * 8];

    // -------- Phase A: att = cf @ kf^T --------
    #pragma unroll
    for (int t = 0; t < 4; ++t) {
        const int nt = wave * 4 + t;         // 8 waves x 4 = 32 n-tiles (512 k)
        floatx4 acc = {0.f, 0.f, 0.f, 0.f};
        #pragma unroll
        for (int ks = 0; ks < 4; ++ks) {
            ushort8 bfrag = *(const ushort8*)(kf_h + (nt * 16 + l16) * 128 + ks * 32 + quad * 8);
            acc = mfma_bf16(afrag[ks], bfrag, acc);
        }
        #pragma unroll
        for (int rr = 0; rr < 4; ++rr)
            att_s[quad * 4 + rr][nt * 16 + l16] = acc[rr];
    }
    __syncthreads();                         // also fences afrag reads of cf_s

    // -------- softmax: wave handles rows 2*wave, 2*wave+1; emit bf16 p_s ----
    #pragma unroll
    for (int rr = 0; rr < 2; ++rr) {
        const int row = wave * 2 + rr;
        float v[8];
        float mx = -1e30f;
        #pragma unroll
        for (int j = 0; j < 8; ++j) {
            v[j] = att_s[row][lane + j * 64];
            mx = fmaxf(mx, v[j]);
        }
        #pragma unroll
        for (int off = 32; off; off >>= 1) mx = fmaxf(mx, __shfl_xor(mx, off));
        float sum = 0.f;
        #pragma unroll
        for (int j = 0; j < 8; ++j) {
            float e = __expf(v[j] - mx);
            p_s[row][lane + j * 64] = f2bf(e);
            sum += e;
        }
        #pragma unroll
        for (int off = 32; off; off >>= 1) sum += __shfl_xor(sum, off);
        if (lane == 0) rowinv_s[row] = 1.0f / sum;
    }
    __syncthreads();

    // -------- Phase B: out_tile = p @ kf  (wave owns d-tile = wave) --------
    floatx4 pacc = {0.f, 0.f, 0.f, 0.f};
    #pragma unroll
    for (int ks = 0; ks < 16; ++ks) {
        ushort8 pa    = *(const ushort8*)&p_s[l16][ks * 32 + quad * 8];
        ushort8 bfrag = *(const ushort8*)(kfT_h + (size_t)(wave * 16 + l16) * 512 + ks * 32 + quad * 8);
        pacc = mfma_bf16(pa, bfrag, pacc);
    }

    // out layout: [Lc, B, D]; hop-sum via atomics (measured free in R4)
    const int d = wave * 16 + l16;
    #pragma unroll
    for (int rr = 0; rr < 4; ++rr)
        atomicAdd(&out[(((size_t)(l0 + quad * 4 + rr)) * 16 + b) * 128 + d],
                  pacc[rr] * rowinv_s[quad * 4 + rr]);
}

extern "C" void kernel_launch(void* const* d_in, const int* in_sizes, int n_in,
                              void* d_out, int out_size, void* d_ws, size_t ws_size,
                              hipStream_t stream) {
    (void)in_sizes; (void)n_in; (void)out_size; (void)ws_size;
    const int*   conv_seqs = (const int*)d_in[0];
    const int*   kb_arr    = (const int*)d_in[1];
    const float* C         = (const float*)d_in[2];
    const float* K         = (const float*)d_in[3];

    // ws layout (bf16): kf [3][16][512][128], kfT [3][16][128][512],
    //                   cf [3*16*16][16][128]
    unsigned short* kf  = (unsigned short*)d_ws;
    unsigned short* kfT = kf  + (size_t)HOPS_ * B_ * LK_ * D_;
    unsigned short* cf  = kfT + (size_t)HOPS_ * B_ * D_ * LK_;
    float* out = (float*)d_out;

    // 1536 kf blocks + 768 cf blocks + 256 zero-out blocks (512 threads each)
    hipLaunchKernelGGL(gather_kernel, dim3(2560), dim3(512), 0, stream,
                       kb_arr, conv_seqs, K, C, kf, kfT, cf, (float4*)out);
    hipLaunchKernelGGL(attn_kernel, dim3(768), dim3(512), 0, stream,
                       cf, kf, kfT, out);
}